// Round 1
// baseline (2687.465 us; speedup 1.0000x reference)
//
#include <hip/hip_runtime.h>

#define NV 500000
#define KOFF 27
#define CIN_ 32
#define COUT_ 64
#define EPS_ 1e-5f

// stats layout (floats, at ws + NV*64):
// [0:64) sum1 [64:128) sumsq1 | [128:192) sum2 [192:256) sumsq2
// [256:320) sumid [320:384) sumsqid
// [384:448) scale1 [448:512) shift1 | [512:576) scale2 [576:640) shift2
// [640:704) scaleid [704:768) shiftid

__global__ void zero_stats_kernel(float* __restrict__ s) {
  if (threadIdx.x < 384) s[threadIdx.x] = 0.f;
}

// Gather-GEMM conv: one thread = one voxel, all 64 output channels in regs.
// w reads are wave-uniform (loop counters only) -> s_load into SGPRs.
template<int CI>
__global__ __launch_bounds__(256) void conv_kernel(
    const float* __restrict__ feats, const int* __restrict__ nbr,
    const float* __restrict__ w, float* __restrict__ out) {
  int i = blockIdx.x * 256 + threadIdx.x;
  int iv = i < NV ? i : 0;
  float acc[COUT_];
#pragma unroll
  for (int c = 0; c < COUT_; ++c) acc[c] = 0.f;

  for (int k = 0; k < KOFF; ++k) {
    int j = nbr[k * NV + iv];
    const float4* row = (const float4*)(feats + (size_t)j * CI);
    const float* wk = w + k * CI * COUT_;
#pragma unroll 2
    for (int q = 0; q < CI / 4; ++q) {
      float4 xv = row[q];
      const float* wq = wk + q * 4 * COUT_;
#pragma unroll
      for (int c = 0; c < COUT_; ++c) acc[c] = fmaf(xv.x, wq[c], acc[c]);
#pragma unroll
      for (int c = 0; c < COUT_; ++c) acc[c] = fmaf(xv.y, wq[COUT_ + c], acc[c]);
#pragma unroll
      for (int c = 0; c < COUT_; ++c) acc[c] = fmaf(xv.z, wq[2 * COUT_ + c], acc[c]);
#pragma unroll
      for (int c = 0; c < COUT_; ++c) acc[c] = fmaf(xv.w, wq[3 * COUT_ + c], acc[c]);
    }
  }
  if (i < NV) {
    float4* o = (float4*)(out + (size_t)i * COUT_);
#pragma unroll
    for (int c4 = 0; c4 < COUT_ / 4; ++c4)
      o[c4] = make_float4(acc[4 * c4], acc[4 * c4 + 1], acc[4 * c4 + 2], acc[4 * c4 + 3]);
  }
}

// per-channel sum + sumsq of a [NV,64] array; lane = channel (coalesced)
__global__ __launch_bounds__(256) void stats_kernel(
    const float* __restrict__ y, float* __restrict__ sums) {
  int lane = threadIdx.x & 63;
  int r0 = blockIdx.x * 4 + (threadIdx.x >> 6);
  int stride = gridDim.x * 4;
  float s = 0.f, ss = 0.f;
  for (int r = r0; r < NV; r += stride) {
    float v = y[(size_t)r * COUT_ + lane];
    s += v;
    ss = fmaf(v, v, ss);
  }
  __shared__ float ls[128];
  if (threadIdx.x < 128) ls[threadIdx.x] = 0.f;
  __syncthreads();
  atomicAdd(&ls[lane], s);
  atomicAdd(&ls[64 + lane], ss);
  __syncthreads();
  if (threadIdx.x < 128) atomicAdd(&sums[threadIdx.x], ls[threadIdx.x]);
}

// stats of x@wid without materializing it; wave = voxel, lane = out channel
__global__ __launch_bounds__(256) void ident_stats_kernel(
    const float* __restrict__ x, const float* __restrict__ wid,
    float* __restrict__ sums) {
  int lane = threadIdx.x & 63;
  int wv = blockIdx.x * 4 + (threadIdx.x >> 6);
  int nw = gridDim.x * 4;
  float wcol[CIN_];
#pragma unroll
  for (int ci = 0; ci < CIN_; ++ci) wcol[ci] = wid[ci * COUT_ + lane];
  float s = 0.f, ss = 0.f;
  for (int v = wv; v < NV; v += nw) {
    const float* xr = x + (size_t)v * CIN_;
    float d = 0.f;
#pragma unroll
    for (int ci = 0; ci < CIN_; ++ci) d = fmaf(xr[ci], wcol[ci], d);
    s += d;
    ss = fmaf(d, d, ss);
  }
  __shared__ float ls[128];
  if (threadIdx.x < 128) ls[threadIdx.x] = 0.f;
  __syncthreads();
  atomicAdd(&ls[lane], s);
  atomicAdd(&ls[64 + lane], ss);
  __syncthreads();
  if (threadIdx.x < 128) atomicAdd(&sums[threadIdx.x], ls[threadIdx.x]);
}

__global__ void finalize_kernel(const float* __restrict__ sums,
                                const float* __restrict__ g,
                                const float* __restrict__ b,
                                float* __restrict__ out) {
  int c = threadIdx.x;  // 64 threads
  float m = sums[c] * (1.0f / NV);
  float var = sums[64 + c] * (1.0f / NV) - m * m;
  float sc = g[c] / sqrtf(var + EPS_);
  out[c] = sc;
  out[64 + c] = b[c] - m * sc;
}

// h = relu(y*scale + shift), in place, float4-vectorized
__global__ __launch_bounds__(256) void bnrelu_kernel(
    float* __restrict__ y, const float* __restrict__ scsh) {
  size_t q = (size_t)blockIdx.x * 256 + threadIdx.x;
  if (q >= (size_t)NV * 16) return;
  int c0 = (int)((q & 15) * 4);
  float4 v = ((const float4*)y)[q];
  v.x = fmaxf(fmaf(v.x, scsh[c0 + 0], scsh[64 + c0 + 0]), 0.f);
  v.y = fmaxf(fmaf(v.y, scsh[c0 + 1], scsh[64 + c0 + 1]), 0.f);
  v.z = fmaxf(fmaf(v.z, scsh[c0 + 2], scsh[64 + c0 + 2]), 0.f);
  v.w = fmaxf(fmaf(v.w, scsh[c0 + 3], scsh[64 + c0 + 3]), 0.f);
  ((float4*)y)[q] = v;
}

// out = relu(bn2(y2) + bnid(x@wid)), y2 in d_out in-place
__global__ __launch_bounds__(256) void final_kernel(
    const float* __restrict__ x, const float* __restrict__ wid,
    float* __restrict__ y2out, const float* __restrict__ ss2,
    const float* __restrict__ ssid) {
  int lane = threadIdx.x & 63;
  int wv = blockIdx.x * 4 + (threadIdx.x >> 6);
  int nw = gridDim.x * 4;
  float wcol[CIN_];
#pragma unroll
  for (int ci = 0; ci < CIN_; ++ci) wcol[ci] = wid[ci * COUT_ + lane];
  float sc2 = ss2[lane], sh2 = ss2[64 + lane];
  float sci = ssid[lane], shi = ssid[64 + lane];
  for (int v = wv; v < NV; v += nw) {
    const float* xr = x + (size_t)v * CIN_;
    float d = 0.f;
#pragma unroll
    for (int ci = 0; ci < CIN_; ++ci) d = fmaf(xr[ci], wcol[ci], d);
    size_t o = (size_t)v * COUT_ + lane;
    float r = fmaf(y2out[o], sc2, sh2) + fmaf(d, sci, shi);
    y2out[o] = fmaxf(r, 0.f);
  }
}

extern "C" void kernel_launch(void* const* d_in, const int* in_sizes, int n_in,
                              void* d_out, int out_size, void* d_ws, size_t ws_size,
                              hipStream_t stream) {
  const float* x   = (const float*)d_in[0];
  const int*   nbr = (const int*)d_in[1];
  const float* w1  = (const float*)d_in[2];
  const float* g1  = (const float*)d_in[3];
  const float* b1  = (const float*)d_in[4];
  const float* w2  = (const float*)d_in[5];
  const float* g2  = (const float*)d_in[6];
  const float* b2  = (const float*)d_in[7];
  const float* wid = (const float*)d_in[8];
  const float* gid = (const float*)d_in[9];
  const float* bid = (const float*)d_in[10];
  float* out = (float*)d_out;

  float* y1 = (float*)d_ws;                    // NV*64 floats (128 MB), later h in-place
  float* st = y1 + (size_t)NV * COUT_;         // 768 floats of stats/affine

  const int convGrid = (NV + 255) / 256;

  zero_stats_kernel<<<1, 384, 0, stream>>>(st);
  conv_kernel<CIN_><<<convGrid, 256, 0, stream>>>(x, nbr, w1, y1);
  stats_kernel<<<1024, 256, 0, stream>>>(y1, st + 0);
  ident_stats_kernel<<<2048, 256, 0, stream>>>(x, wid, st + 256);
  finalize_kernel<<<1, 64, 0, stream>>>(st + 0, g1, b1, st + 384);
  finalize_kernel<<<1, 64, 0, stream>>>(st + 256, gid, bid, st + 640);
  bnrelu_kernel<<<(NV * 16 + 255) / 256, 256, 0, stream>>>(y1, st + 384);
  conv_kernel<COUT_><<<convGrid, 256, 0, stream>>>(y1, nbr, w2, out);
  stats_kernel<<<1024, 256, 0, stream>>>(out, st + 128);
  finalize_kernel<<<1, 64, 0, stream>>>(st + 128, g2, b2, st + 512);
  final_kernel<<<4096, 256, 0, stream>>>(x, wid, out, st + 512, st + 640);
}

// Round 2
// 1861.636 us; speedup vs baseline: 1.4436x; 1.4436x over previous
//
#include <hip/hip_runtime.h>

#define NV 500000
#define KOFF 27
#define CIN_ 32
#define COUT_ 64
#define EPS_ 1e-5f

typedef __attribute__((ext_vector_type(8))) _Float16 half8;
typedef __attribute__((ext_vector_type(4))) float floatx4;

// ws layout:
//   y1h  : NV*64 f16   (conv1 out, then h in-place)
//   xh   : NV*32 f16   (x cast)
//   wT1  : 27*64*32 f16 (w1 transposed [k][co][ci])
//   wT2  : 27*64*64 f16
//   st   : 768 floats  (sums + affine, layout as round 1)

__global__ void zero_stats_kernel(float* __restrict__ s) {
  if (threadIdx.x < 384) s[threadIdx.x] = 0.f;
}

__global__ __launch_bounds__(256) void cast_x_kernel(
    const float* __restrict__ x, _Float16* __restrict__ xh) {
  size_t q = (size_t)blockIdx.x * 256 + threadIdx.x;  // 8 floats each
  if (q >= (size_t)NV * CIN_ / 8) return;
  const float4* xp = (const float4*)x;
  float4 a = xp[2 * q], b = xp[2 * q + 1];
  half8 h;
  h[0] = (_Float16)a.x; h[1] = (_Float16)a.y; h[2] = (_Float16)a.z; h[3] = (_Float16)a.w;
  h[4] = (_Float16)b.x; h[5] = (_Float16)b.y; h[6] = (_Float16)b.z; h[7] = (_Float16)b.w;
  ((half8*)xh)[q] = h;
}

// wT[k][co][ci] = (f16) w[k][ci][co]
__global__ void wtrans_kernel(const float* __restrict__ w,
                              _Float16* __restrict__ wT, int CI) {
  int t = blockIdx.x * 256 + threadIdx.x;
  int total = KOFF * CI * COUT_;
  if (t >= total) return;
  int k = t / (CI * COUT_);
  int r = t % (CI * COUT_);
  int co = r / CI;
  int ci = r % CI;
  wT[t] = (_Float16)w[(k * CI + ci) * COUT_ + co];
}

// MFMA gather-conv: wave = 16 voxels x 64 out channels.
// A frag: lane holds A[m=lane&15][k=quad*8+j]; B frag: B[k=quad*8+j][n=lane&15]
// C/D:   lane reg r holds D[row=quad*4+r][col=lane&15]
template<int CI, bool WRITE_F16>
__global__ __launch_bounds__(256) void conv_mfma_kernel(
    const _Float16* __restrict__ feats, const int* __restrict__ nbr,
    const _Float16* __restrict__ wT, float* __restrict__ outF,
    _Float16* __restrict__ outH) {
  int gwave = (blockIdx.x * 256 + threadIdx.x) >> 6;
  int lane = threadIdx.x & 63;
  int vbase = gwave * 16;
  if (vbase >= NV) return;
  int m = lane & 15;
  int quad = lane >> 4;
  int vox = vbase + m;

  floatx4 acc[4];
#pragma unroll
  for (int nf = 0; nf < 4; ++nf) acc[nf] = (floatx4){0.f, 0.f, 0.f, 0.f};

  for (int k = 0; k < KOFF; ++k) {
    int j = nbr[k * NV + vox];
    const half8* arow = (const half8*)(feats + (size_t)j * CI);
    const _Float16* wk = wT + (size_t)k * COUT_ * CI;
#pragma unroll
    for (int s = 0; s < CI / 32; ++s) {
      half8 afrag = arow[s * 4 + quad];
#pragma unroll
      for (int nf = 0; nf < 4; ++nf) {
        half8 bfrag = *(const half8*)(wk + (size_t)(nf * 16 + m) * CI + s * 32 + quad * 8);
        acc[nf] = __builtin_amdgcn_mfma_f32_16x16x32_f16(afrag, bfrag, acc[nf], 0, 0, 0);
      }
    }
  }

#pragma unroll
  for (int nf = 0; nf < 4; ++nf) {
#pragma unroll
    for (int r = 0; r < 4; ++r) {
      size_t o = (size_t)(vbase + quad * 4 + r) * COUT_ + nf * 16 + m;
      if (WRITE_F16) outH[o] = (_Float16)acc[nf][r];
      else outF[o] = acc[nf][r];
    }
  }
}

// per-channel sum + sumsq, f16 input
__global__ __launch_bounds__(256) void stats_f16_kernel(
    const _Float16* __restrict__ y, float* __restrict__ sums) {
  int lane = threadIdx.x & 63;
  int r0 = blockIdx.x * 4 + (threadIdx.x >> 6);
  int stride = gridDim.x * 4;
  float s = 0.f, ss = 0.f;
  for (int r = r0; r < NV; r += stride) {
    float v = (float)y[(size_t)r * COUT_ + lane];
    s += v;
    ss = fmaf(v, v, ss);
  }
  __shared__ float ls[128];
  if (threadIdx.x < 128) ls[threadIdx.x] = 0.f;
  __syncthreads();
  atomicAdd(&ls[lane], s);
  atomicAdd(&ls[64 + lane], ss);
  __syncthreads();
  if (threadIdx.x < 128) atomicAdd(&sums[threadIdx.x], ls[threadIdx.x]);
}

__global__ __launch_bounds__(256) void stats_f32_kernel(
    const float* __restrict__ y, float* __restrict__ sums) {
  int lane = threadIdx.x & 63;
  int r0 = blockIdx.x * 4 + (threadIdx.x >> 6);
  int stride = gridDim.x * 4;
  float s = 0.f, ss = 0.f;
  for (int r = r0; r < NV; r += stride) {
    float v = y[(size_t)r * COUT_ + lane];
    s += v;
    ss = fmaf(v, v, ss);
  }
  __shared__ float ls[128];
  if (threadIdx.x < 128) ls[threadIdx.x] = 0.f;
  __syncthreads();
  atomicAdd(&ls[lane], s);
  atomicAdd(&ls[64 + lane], ss);
  __syncthreads();
  if (threadIdx.x < 128) atomicAdd(&sums[threadIdx.x], ls[threadIdx.x]);
}

// stats of x@wid without materializing it
__global__ __launch_bounds__(256) void ident_stats_kernel(
    const float* __restrict__ x, const float* __restrict__ wid,
    float* __restrict__ sums) {
  int lane = threadIdx.x & 63;
  int wv = blockIdx.x * 4 + (threadIdx.x >> 6);
  int nw = gridDim.x * 4;
  float wcol[CIN_];
#pragma unroll
  for (int ci = 0; ci < CIN_; ++ci) wcol[ci] = wid[ci * COUT_ + lane];
  float s = 0.f, ss = 0.f;
  for (int v = wv; v < NV; v += nw) {
    const float* xr = x + (size_t)v * CIN_;
    float d = 0.f;
#pragma unroll
    for (int ci = 0; ci < CIN_; ++ci) d = fmaf(xr[ci], wcol[ci], d);
    s += d;
    ss = fmaf(d, d, ss);
  }
  __shared__ float ls[128];
  if (threadIdx.x < 128) ls[threadIdx.x] = 0.f;
  __syncthreads();
  atomicAdd(&ls[lane], s);
  atomicAdd(&ls[64 + lane], ss);
  __syncthreads();
  if (threadIdx.x < 128) atomicAdd(&sums[threadIdx.x], ls[threadIdx.x]);
}

__global__ void finalize_kernel(const float* __restrict__ sums,
                                const float* __restrict__ g,
                                const float* __restrict__ b,
                                float* __restrict__ out) {
  int c = threadIdx.x;  // 64 threads
  float m = sums[c] * (1.0f / NV);
  float var = sums[64 + c] * (1.0f / NV) - m * m;
  float sc = g[c] / sqrtf(var + EPS_);
  out[c] = sc;
  out[64 + c] = b[c] - m * sc;
}

// h = relu(y*scale + shift), f16 in-place, 8 elems/thread
__global__ __launch_bounds__(256) void bnrelu_f16_kernel(
    _Float16* __restrict__ y, const float* __restrict__ scsh) {
  size_t q = (size_t)blockIdx.x * 256 + threadIdx.x;
  if (q >= (size_t)NV * COUT_ / 8) return;
  int c0 = (int)(q & 7) * 8;
  half8 v = ((const half8*)y)[q];
#pragma unroll
  for (int jj = 0; jj < 8; ++jj) {
    float f = fmaxf(fmaf((float)v[jj], scsh[c0 + jj], scsh[64 + c0 + jj]), 0.f);
    v[jj] = (_Float16)f;
  }
  ((half8*)y)[q] = v;
}

// out = relu(bn2(y2) + bnid(x@wid)), y2 = d_out in-place
__global__ __launch_bounds__(256) void final_kernel(
    const float* __restrict__ x, const float* __restrict__ wid,
    float* __restrict__ y2out, const float* __restrict__ ss2,
    const float* __restrict__ ssid) {
  int lane = threadIdx.x & 63;
  int wv = blockIdx.x * 4 + (threadIdx.x >> 6);
  int nw = gridDim.x * 4;
  float wcol[CIN_];
#pragma unroll
  for (int ci = 0; ci < CIN_; ++ci) wcol[ci] = wid[ci * COUT_ + lane];
  float sc2 = ss2[lane], sh2 = ss2[64 + lane];
  float sci = ssid[lane], shi = ssid[64 + lane];
  for (int v = wv; v < NV; v += nw) {
    const float* xr = x + (size_t)v * CIN_;
    float d = 0.f;
#pragma unroll
    for (int ci = 0; ci < CIN_; ++ci) d = fmaf(xr[ci], wcol[ci], d);
    size_t o = (size_t)v * COUT_ + lane;
    float r = fmaf(y2out[o], sc2, sh2) + fmaf(d, sci, shi);
    y2out[o] = fmaxf(r, 0.f);
  }
}

extern "C" void kernel_launch(void* const* d_in, const int* in_sizes, int n_in,
                              void* d_out, int out_size, void* d_ws, size_t ws_size,
                              hipStream_t stream) {
  const float* x   = (const float*)d_in[0];
  const int*   nbr = (const int*)d_in[1];
  const float* w1  = (const float*)d_in[2];
  const float* g1  = (const float*)d_in[3];
  const float* b1  = (const float*)d_in[4];
  const float* w2  = (const float*)d_in[5];
  const float* g2  = (const float*)d_in[6];
  const float* b2  = (const float*)d_in[7];
  const float* wid = (const float*)d_in[8];
  const float* gid = (const float*)d_in[9];
  const float* bid = (const float*)d_in[10];
  float* out = (float*)d_out;

  _Float16* y1h = (_Float16*)d_ws;                   // NV*64
  _Float16* xh  = y1h + (size_t)NV * COUT_;          // NV*32
  _Float16* wT1 = xh + (size_t)NV * CIN_;            // 27*64*32
  _Float16* wT2 = wT1 + KOFF * COUT_ * CIN_;         // 27*64*64
  float*    st  = (float*)(wT2 + KOFF * COUT_ * COUT_);

  const int convBlocks = (NV / 16 + 3) / 4;  // 31250 waves, 4/block -> 7813

  zero_stats_kernel<<<1, 384, 0, stream>>>(st);
  cast_x_kernel<<<(NV * CIN_ / 8 + 255) / 256, 256, 0, stream>>>(x, xh);
  wtrans_kernel<<<(KOFF * CIN_ * COUT_ + 255) / 256, 256, 0, stream>>>(w1, wT1, CIN_);
  wtrans_kernel<<<(KOFF * COUT_ * COUT_ + 255) / 256, 256, 0, stream>>>(w2, wT2, COUT_);

  conv_mfma_kernel<CIN_, true><<<convBlocks, 256, 0, stream>>>(xh, nbr, wT1, nullptr, y1h);
  stats_f16_kernel<<<2048, 256, 0, stream>>>(y1h, st + 0);
  ident_stats_kernel<<<2048, 256, 0, stream>>>(x, wid, st + 256);
  finalize_kernel<<<1, 64, 0, stream>>>(st + 0, g1, b1, st + 384);
  finalize_kernel<<<1, 64, 0, stream>>>(st + 256, gid, bid, st + 640);
  bnrelu_f16_kernel<<<(NV * COUT_ / 8 + 255) / 256, 256, 0, stream>>>(y1h, st + 384);

  conv_mfma_kernel<COUT_, false><<<convBlocks, 256, 0, stream>>>(y1h, nbr, wT2, out, nullptr);
  stats_f32_kernel<<<2048, 256, 0, stream>>>(out, st + 128);
  finalize_kernel<<<1, 64, 0, stream>>>(st + 128, g2, b2, st + 512);
  final_kernel<<<4096, 256, 0, stream>>>(x, wid, out, st + 512, st + 640);
}

// Round 3
// 1181.704 us; speedup vs baseline: 2.2742x; 1.5754x over previous
//
#include <hip/hip_runtime.h>

#define NV 500000
#define KOFF 27
#define CIN_ 32
#define COUT_ 64
#define EPS_ 1e-5f

typedef __attribute__((ext_vector_type(8))) _Float16 half8;
typedef __attribute__((ext_vector_type(4))) float floatx4;

// ws layout: y1h NV*64 f16 | xh NV*32 f16 | wT1 27*64*32 f16 | wT2 27*64*64 f16 | st 768 f32

__global__ void zero_stats_kernel(float* __restrict__ s) {
  if (threadIdx.x < 384) s[threadIdx.x] = 0.f;
}

__global__ __launch_bounds__(256) void cast_x_kernel(
    const float* __restrict__ x, _Float16* __restrict__ xh) {
  size_t q = (size_t)blockIdx.x * 256 + threadIdx.x;
  if (q >= (size_t)NV * CIN_ / 8) return;
  const float4* xp = (const float4*)x;
  float4 a = xp[2 * q], b = xp[2 * q + 1];
  half8 h;
  h[0] = (_Float16)a.x; h[1] = (_Float16)a.y; h[2] = (_Float16)a.z; h[3] = (_Float16)a.w;
  h[4] = (_Float16)b.x; h[5] = (_Float16)b.y; h[6] = (_Float16)b.z; h[7] = (_Float16)b.w;
  ((half8*)xh)[q] = h;
}

// wT[k][co][ci] = (f16) w[k][ci][co]
__global__ void wtrans_kernel(const float* __restrict__ w,
                              _Float16* __restrict__ wT, int CI) {
  int t = blockIdx.x * 256 + threadIdx.x;
  int total = KOFF * CI * COUT_;
  if (t >= total) return;
  int k = t / (CI * COUT_);
  int r = t % (CI * COUT_);
  int co = r / CI;
  int ci = r % CI;
  wT[t] = (_Float16)w[(k * CI + ci) * COUT_ + co];
}

// ---- conv v3: LDS-staged B (lgkmcnt) + register ring of gathered A (vmcnt) ----

template<int CI>
__device__ __forceinline__ void stageB(const _Float16* __restrict__ wT,
                                       _Float16* __restrict__ lds,
                                       int k0, int kp, int tid) {
  __syncthreads();  // all waves done reading previous phase's LDS
  const int segs = CI / 8;
  const int chunks = kp * COUT_ * segs;
  for (int idx = tid; idx < chunks; idx += 1024) {
    int row = idx / segs;
    int s = idx - row * segs;
    half8 v = *(const half8*)(wT + ((size_t)k0 * COUT_ + row) * CI + s * 8);
    *(half8*)(lds + (size_t)row * (CI + 8) + s * 8) = v;
  }
  __syncthreads();
}

template<int CI, int KPC, int D>
__device__ __forceinline__ void run_phase(
    const half8* __restrict__ fp, const int* __restrict__ nbr,
    const _Float16* __restrict__ lds, int k0,
    int v0, int v1, int m, int quad, floatx4 acc[2][4]) {
  constexpr int SEG = CI / 32;
  constexpr int ROWH8 = CI / 8;

  // preload ALL phase indices first: later address consumption never waits
  // on a recently-issued load (vmcnt drains in order)
  int j0[KPC], j1[KPC];
#pragma unroll
  for (int k = 0; k < KPC; ++k) {
    j0[k] = nbr[(k0 + k) * NV + v0] * ROWH8;
    j1[k] = nbr[(k0 + k) * NV + v1] * ROWH8;
  }

  half8 ring[D][2][SEG];
#pragma unroll
  for (int p = 0; p < D; ++p) {
#pragma unroll
    for (int s = 0; s < SEG; ++s) {
      ring[p][0][s] = fp[(size_t)j0[p] + s * 4 + quad];
      ring[p][1][s] = fp[(size_t)j1[p] + s * 4 + quad];
    }
  }

#pragma unroll
  for (int k = 0; k < KPC; ++k) {
    const _Float16* bk = lds + (size_t)k * COUT_ * (CI + 8);
#pragma unroll
    for (int s = 0; s < SEG; ++s) {
#pragma unroll
      for (int nf = 0; nf < 4; ++nf) {
        half8 bf = *(const half8*)(bk + (nf * 16 + m) * (CI + 8) + s * 32 + quad * 8);
        acc[0][nf] = __builtin_amdgcn_mfma_f32_16x16x32_f16(ring[k % D][0][s], bf, acc[0][nf], 0, 0, 0);
        acc[1][nf] = __builtin_amdgcn_mfma_f32_16x16x32_f16(ring[k % D][1][s], bf, acc[1][nf], 0, 0, 0);
      }
    }
    if (k + D < KPC) {
#pragma unroll
      for (int s = 0; s < SEG; ++s) {
        ring[k % D][0][s] = fp[(size_t)j0[k + D] + s * 4 + quad];
        ring[k % D][1][s] = fp[(size_t)j1[k + D] + s * 4 + quad];
      }
    }
  }
}

template<int CI, bool WF16>
__global__ __launch_bounds__(1024, 4) void conv_mfma_v3(
    const _Float16* __restrict__ feats, const int* __restrict__ nbr,
    const _Float16* __restrict__ wT, float* __restrict__ outF,
    _Float16* __restrict__ outH) {
  constexpr int LDSH = (CI == 64) ? 7 * 64 * 72 : 9 * 64 * 40;
  __shared__ __align__(16) _Float16 ldsB[LDSH];

  int tid = threadIdx.x;
  int wave = tid >> 6, lane = tid & 63;
  int m = lane & 15, quad = lane >> 4;
  int vbase = (blockIdx.x * 16 + wave) * 32;  // 32 voxels per wave
  int v0 = vbase + m;
  int v1 = vbase + 16 + m;
  v0 = v0 < NV ? v0 : NV - 1;
  v1 = v1 < NV ? v1 : NV - 1;
  const half8* fp = (const half8*)feats;

  floatx4 acc[2][4];
#pragma unroll
  for (int g = 0; g < 2; ++g)
#pragma unroll
    for (int nf = 0; nf < 4; ++nf) acc[g][nf] = (floatx4){0.f, 0.f, 0.f, 0.f};

  if constexpr (CI == 64) {
    stageB<CI>(wT, ldsB, 0, 7, tid);
    run_phase<CI, 7, 3>(fp, nbr, ldsB, 0, v0, v1, m, quad, acc);
    stageB<CI>(wT, ldsB, 7, 7, tid);
    run_phase<CI, 7, 3>(fp, nbr, ldsB, 7, v0, v1, m, quad, acc);
    stageB<CI>(wT, ldsB, 14, 7, tid);
    run_phase<CI, 7, 3>(fp, nbr, ldsB, 14, v0, v1, m, quad, acc);
    stageB<CI>(wT, ldsB, 21, 6, tid);
    run_phase<CI, 6, 3>(fp, nbr, ldsB, 21, v0, v1, m, quad, acc);
  } else {
    stageB<CI>(wT, ldsB, 0, 9, tid);
    run_phase<CI, 9, 4>(fp, nbr, ldsB, 0, v0, v1, m, quad, acc);
    stageB<CI>(wT, ldsB, 9, 9, tid);
    run_phase<CI, 9, 4>(fp, nbr, ldsB, 9, v0, v1, m, quad, acc);
    stageB<CI>(wT, ldsB, 18, 9, tid);
    run_phase<CI, 9, 4>(fp, nbr, ldsB, 18, v0, v1, m, quad, acc);
  }

#pragma unroll
  for (int g = 0; g < 2; ++g)
#pragma unroll
    for (int nf = 0; nf < 4; ++nf)
#pragma unroll
      for (int r = 0; r < 4; ++r) {
        int row = vbase + g * 16 + quad * 4 + r;
        if (row < NV) {
          size_t o = (size_t)row * COUT_ + nf * 16 + m;
          if (WF16) outH[o] = (_Float16)acc[g][nf][r];
          else outF[o] = acc[g][nf][r];
        }
      }
}

// ---- stats / BN / epilogue (unchanged from round 2) ----

__global__ __launch_bounds__(256) void stats_f16_kernel(
    const _Float16* __restrict__ y, float* __restrict__ sums) {
  int lane = threadIdx.x & 63;
  int r0 = blockIdx.x * 4 + (threadIdx.x >> 6);
  int stride = gridDim.x * 4;
  float s = 0.f, ss = 0.f;
  for (int r = r0; r < NV; r += stride) {
    float v = (float)y[(size_t)r * COUT_ + lane];
    s += v;
    ss = fmaf(v, v, ss);
  }
  __shared__ float ls[128];
  if (threadIdx.x < 128) ls[threadIdx.x] = 0.f;
  __syncthreads();
  atomicAdd(&ls[lane], s);
  atomicAdd(&ls[64 + lane], ss);
  __syncthreads();
  if (threadIdx.x < 128) atomicAdd(&sums[threadIdx.x], ls[threadIdx.x]);
}

__global__ __launch_bounds__(256) void stats_f32_kernel(
    const float* __restrict__ y, float* __restrict__ sums) {
  int lane = threadIdx.x & 63;
  int r0 = blockIdx.x * 4 + (threadIdx.x >> 6);
  int stride = gridDim.x * 4;
  float s = 0.f, ss = 0.f;
  for (int r = r0; r < NV; r += stride) {
    float v = y[(size_t)r * COUT_ + lane];
    s += v;
    ss = fmaf(v, v, ss);
  }
  __shared__ float ls[128];
  if (threadIdx.x < 128) ls[threadIdx.x] = 0.f;
  __syncthreads();
  atomicAdd(&ls[lane], s);
  atomicAdd(&ls[64 + lane], ss);
  __syncthreads();
  if (threadIdx.x < 128) atomicAdd(&sums[threadIdx.x], ls[threadIdx.x]);
}

__global__ __launch_bounds__(256) void ident_stats_kernel(
    const float* __restrict__ x, const float* __restrict__ wid,
    float* __restrict__ sums) {
  int lane = threadIdx.x & 63;
  int wv = blockIdx.x * 4 + (threadIdx.x >> 6);
  int nw = gridDim.x * 4;
  float wcol[CIN_];
#pragma unroll
  for (int ci = 0; ci < CIN_; ++ci) wcol[ci] = wid[ci * COUT_ + lane];
  float s = 0.f, ss = 0.f;
  for (int v = wv; v < NV; v += nw) {
    const float* xr = x + (size_t)v * CIN_;
    float d = 0.f;
#pragma unroll
    for (int ci = 0; ci < CIN_; ++ci) d = fmaf(xr[ci], wcol[ci], d);
    s += d;
    ss = fmaf(d, d, ss);
  }
  __shared__ float ls[128];
  if (threadIdx.x < 128) ls[threadIdx.x] = 0.f;
  __syncthreads();
  atomicAdd(&ls[lane], s);
  atomicAdd(&ls[64 + lane], ss);
  __syncthreads();
  if (threadIdx.x < 128) atomicAdd(&sums[threadIdx.x], ls[threadIdx.x]);
}

__global__ void finalize_kernel(const float* __restrict__ sums,
                                const float* __restrict__ g,
                                const float* __restrict__ b,
                                float* __restrict__ out) {
  int c = threadIdx.x;
  float m = sums[c] * (1.0f / NV);
  float var = sums[64 + c] * (1.0f / NV) - m * m;
  float sc = g[c] / sqrtf(var + EPS_);
  out[c] = sc;
  out[64 + c] = b[c] - m * sc;
}

__global__ __launch_bounds__(256) void bnrelu_f16_kernel(
    _Float16* __restrict__ y, const float* __restrict__ scsh) {
  size_t q = (size_t)blockIdx.x * 256 + threadIdx.x;
  if (q >= (size_t)NV * COUT_ / 8) return;
  int c0 = (int)(q & 7) * 8;
  half8 v = ((const half8*)y)[q];
#pragma unroll
  for (int jj = 0; jj < 8; ++jj) {
    float f = fmaxf(fmaf((float)v[jj], scsh[c0 + jj], scsh[64 + c0 + jj]), 0.f);
    v[jj] = (_Float16)f;
  }
  ((half8*)y)[q] = v;
}

__global__ __launch_bounds__(256) void final_kernel(
    const float* __restrict__ x, const float* __restrict__ wid,
    float* __restrict__ y2out, const float* __restrict__ ss2,
    const float* __restrict__ ssid) {
  int lane = threadIdx.x & 63;
  int wv = blockIdx.x * 4 + (threadIdx.x >> 6);
  int nw = gridDim.x * 4;
  float wcol[CIN_];
#pragma unroll
  for (int ci = 0; ci < CIN_; ++ci) wcol[ci] = wid[ci * COUT_ + lane];
  float sc2 = ss2[lane], sh2 = ss2[64 + lane];
  float sci = ssid[lane], shi = ssid[64 + lane];
  for (int v = wv; v < NV; v += nw) {
    const float* xr = x + (size_t)v * CIN_;
    float d = 0.f;
#pragma unroll
    for (int ci = 0; ci < CIN_; ++ci) d = fmaf(xr[ci], wcol[ci], d);
    size_t o = (size_t)v * COUT_ + lane;
    float r = fmaf(y2out[o], sc2, sh2) + fmaf(d, sci, shi);
    y2out[o] = fmaxf(r, 0.f);
  }
}

extern "C" void kernel_launch(void* const* d_in, const int* in_sizes, int n_in,
                              void* d_out, int out_size, void* d_ws, size_t ws_size,
                              hipStream_t stream) {
  const float* x   = (const float*)d_in[0];
  const int*   nbr = (const int*)d_in[1];
  const float* w1  = (const float*)d_in[2];
  const float* g1  = (const float*)d_in[3];
  const float* b1  = (const float*)d_in[4];
  const float* w2  = (const float*)d_in[5];
  const float* g2  = (const float*)d_in[6];
  const float* b2  = (const float*)d_in[7];
  const float* wid = (const float*)d_in[8];
  const float* gid = (const float*)d_in[9];
  const float* bid = (const float*)d_in[10];
  float* out = (float*)d_out;

  _Float16* y1h = (_Float16*)d_ws;
  _Float16* xh  = y1h + (size_t)NV * COUT_;
  _Float16* wT1 = xh + (size_t)NV * CIN_;
  _Float16* wT2 = wT1 + KOFF * COUT_ * CIN_;
  float*    st  = (float*)(wT2 + KOFF * COUT_ * COUT_);

  const int NWG = (NV + 511) / 512;  // 1024 thr = 16 waves x 32 voxels

  zero_stats_kernel<<<1, 384, 0, stream>>>(st);
  cast_x_kernel<<<(NV * CIN_ / 8 + 255) / 256, 256, 0, stream>>>(x, xh);
  wtrans_kernel<<<(KOFF * CIN_ * COUT_ + 255) / 256, 256, 0, stream>>>(w1, wT1, CIN_);
  wtrans_kernel<<<(KOFF * COUT_ * COUT_ + 255) / 256, 256, 0, stream>>>(w2, wT2, COUT_);

  conv_mfma_v3<CIN_, true><<<NWG, 1024, 0, stream>>>(xh, nbr, wT1, nullptr, y1h);
  stats_f16_kernel<<<2048, 256, 0, stream>>>(y1h, st + 0);
  ident_stats_kernel<<<2048, 256, 0, stream>>>(x, wid, st + 256);
  finalize_kernel<<<1, 64, 0, stream>>>(st + 0, g1, b1, st + 384);
  finalize_kernel<<<1, 64, 0, stream>>>(st + 256, gid, bid, st + 640);
  bnrelu_f16_kernel<<<(NV * COUT_ / 8 + 255) / 256, 256, 0, stream>>>(y1h, st + 384);

  conv_mfma_v3<COUT_, false><<<NWG, 1024, 0, stream>>>(y1h, nbr, wT2, out, nullptr);
  stats_f32_kernel<<<2048, 256, 0, stream>>>(out, st + 128);
  finalize_kernel<<<1, 64, 0, stream>>>(st + 128, g2, b2, st + 512);
  final_kernel<<<4096, 256, 0, stream>>>(x, wid, out, st + 512, st + 640);
}